// Round 2
// baseline (1718.408 us; speedup 1.0000x reference)
//
#include <hip/hip_runtime.h>

#define BATCH 256
#define TSTEPS 4096
#define HID 136
#define HPAD 144      // padded hidden: 4 aligned chunks of 36 floats (144 B each)
#define ODIM 68
#define KR 36         // k-chunk per ks lane (36 floats = 9 float4, 16B aligned)
#define THREADS 512   // 8 full waves, exactly 2 per SIMD

__device__ __forceinline__ float fast_tanh(float z) {
    float az = fabsf(z);
    float e = __expf(-2.0f * az);
    float r = (1.0f - e) * __builtin_amdgcn_rcpf(1.0f + e);
    return copysignf(r, z);
}

// quad butterfly stages on the VALU pipe (DPP), not the LDS pipe
__device__ __forceinline__ float dpp_xor1_add(float x) {   // lane ^ 1
    int y = __builtin_amdgcn_update_dpp(0, __float_as_int(x), 0xB1, 0xF, 0xF, false);
    return x + __int_as_float(y);
}
__device__ __forceinline__ float dpp_xor2_add(float x) {   // lane ^ 2
    int y = __builtin_amdgcn_update_dpp(0, __float_as_int(x), 0x4E, 0xF, 0xF, false);
    return x + __int_as_float(y);
}

// One recurrence step: read HR, write HW. All addresses loop-invariant.
#define RNN_STEP(HR, HW, T)                                                   \
    {                                                                         \
        const float4* hp = (const float4*)((HR) + k0);                        \
        float4 he = *(const float4*)((HR) + kec);                             \
        float p0 = 0.f, p1 = 0.f, p2 = 0.f, p3 = 0.f;                         \
        _Pragma("unroll")                                                     \
        for (int i = 0; i < KR / 4; ++i) {                                    \
            float4 h4 = hp[i];                                                \
            p0 = fmaf(h4.x, wm[4 * i + 0], p0);                               \
            p1 = fmaf(h4.y, wm[4 * i + 1], p1);                               \
            p2 = fmaf(h4.z, wm[4 * i + 2], p2);                               \
            p3 = fmaf(h4.w, wm[4 * i + 3], p3);                               \
        }                                                                     \
        float pe = he.x * we[0];                                              \
        pe = fmaf(he.y, we[1], pe);                                           \
        pe = fmaf(he.z, we[2], pe);                                           \
        pe = fmaf(he.w, we[3], pe);                                           \
        float pm = (p0 + p1) + (p2 + p3);                                     \
        pm = dpp_xor1_add(pm);                                                \
        pm = dpp_xor2_add(pm);      /* all 4 quad lanes hold full main sum */ \
        pe = dpp_xor1_add(pe);                                                \
        pe = dpp_xor2_add(pe);                                                \
        pe += __shfl_xor(pe, 4);                                              \
        pe += __shfl_xor(pe, 8);                                              \
        pe += __shfl_xor(pe, 16);                                             \
        pe += __shfl_xor(pe, 32);   /* all 64 lanes hold full extra sum */    \
        float2 xv = *(const float2*)(xs + 2 * (T));                           \
        float zm = fmaf(xv.x, wih0, fmaf(xv.y, wih1, bjm)) + pm;              \
        float ze = fmaf(xv.x, wie0, fmaf(xv.y, wie1, bje)) + pe;              \
        float th = fast_tanh((lane == 1) ? ze : zm);                          \
        if (ks == 0 || lane == 1) {                                           \
            (HW)[(lane == 1) ? er : jq] = th;                                 \
        }                                                                     \
    }

__global__ __launch_bounds__(THREADS)
void rnn_fused_kernel(const float* __restrict__ x,
                      const float* __restrict__ W_ih,
                      const float* __restrict__ W_hh,
                      const float* __restrict__ b_ih,
                      const float* __restrict__ b_hh,
                      const float* __restrict__ W_fc,
                      const float* __restrict__ b_fc,
                      float* __restrict__ out)
{
    __shared__ __align__(16) float xs[TSTEPS * 2];   // 32 KB: x[b,:,:]
    __shared__ __align__(16) float hA[HPAD];
    __shared__ __align__(16) float hB[HPAD];

    const int b    = blockIdx.x;
    const int tid  = threadIdx.x;
    const int lane = tid & 63;
    const int wv   = tid >> 6;          // wave 0..7
    const int jq   = tid >> 2;          // main row 0..127 (one per quad)
    const int ks   = tid & 3;           // k-split lane within quad
    const int k0   = ks * KR;

    // ---- persistent weights in registers ----
    float wm[KR];                       // main row W_hh chunk (zero-padded)
#pragma unroll
    for (int i = 0; i < KR; ++i) {
        int k = k0 + i;
        wm[i] = (k < HID) ? W_hh[jq * HID + k] : 0.0f;
    }
    const float wih0 = W_ih[jq * 2 + 0];
    const float wih1 = W_ih[jq * 2 + 1];
    const float bjm  = b_ih[jq] + b_hh[jq];

    // extra row (128+wave), k split 4-per-lane across lanes 0..35
    const int er  = 128 + wv;
    const int kec = (lane < 36) ? (lane * 4) : 0;   // aligned b128 source
    float we[4];
#pragma unroll
    for (int q = 0; q < 4; ++q) {
        int k = lane * 4 + q;
        we[q] = (lane < 36 && k < HID) ? W_hh[er * HID + k] : 0.0f;
    }
    const float wie0 = W_ih[er * 2 + 0];
    const float wie1 = W_ih[er * 2 + 1];
    const float bje  = b_ih[er] + b_hh[er];

    // ---- stage x[b] into LDS (coalesced float4) ----
    {
        const float4* xg = (const float4*)(x + (size_t)b * (TSTEPS * 2));
        float4* xl = (float4*)xs;
        for (int i = tid; i < TSTEPS * 2 / 4; i += THREADS) xl[i] = xg[i];
    }
    // zero both h buffers (padding 136..143 stays zero forever)
    for (int i = tid; i < HPAD; i += THREADS) { hA[i] = 0.0f; hB[i] = 0.0f; }
    __syncthreads();

    // ---- recurrence, unrolled x2 (fixed buffers, no cur arithmetic) ----
    for (int t = 0; t < TSTEPS; t += 2) {
        RNN_STEP(hA, hB, t);
        __syncthreads();
        RNN_STEP(hB, hA, t + 1);
        __syncthreads();
    }
    // TSTEPS even -> final h in hA

    // ---- final head: out[b][o] = h . W_fc[o,:] + b_fc[o] ----
    if (tid < ODIM * 4) {
        int o = tid >> 2;
        float p = 0.f;
#pragma unroll
        for (int i = 0; i < KR; ++i) {
            int k = k0 + i;
            if (k < HID) p = fmaf(hA[k], W_fc[o * HID + k], p);
        }
        p = dpp_xor1_add(p);
        p = dpp_xor2_add(p);
        if (ks == 0) out[b * ODIM + o] = p + b_fc[o];
    }
}

extern "C" void kernel_launch(void* const* d_in, const int* in_sizes, int n_in,
                              void* d_out, int out_size, void* d_ws, size_t ws_size,
                              hipStream_t stream) {
    const float* x    = (const float*)d_in[0];
    const float* W_ih = (const float*)d_in[1];
    const float* W_hh = (const float*)d_in[2];
    const float* b_ih = (const float*)d_in[3];
    const float* b_hh = (const float*)d_in[4];
    const float* W_fc = (const float*)d_in[5];
    const float* b_fc = (const float*)d_in[6];
    float* out = (float*)d_out;

    rnn_fused_kernel<<<BATCH, THREADS, 0, stream>>>(x, W_ih, W_hh, b_ih, b_hh,
                                                    W_fc, b_fc, out);
}